// Round 1
// baseline (346.045 us; speedup 1.0000x reference)
//
#include <hip/hip_runtime.h>
#include <math.h>

#define B 4
#define SEQ 8192
#define DIM 1024
#define HEADS 8
#define NCHUNK 128
#define CLEN (SEQ / NCHUNK)   // 64
#define LN_EPS 1e-5f

// ---------------------------------------------------------------------------
// K1: LayerNorm stats — one wave (64 lanes) per row of 1024 floats.
// ---------------------------------------------------------------------------
__global__ void ln_stats_kernel(const float* __restrict__ x,
                                float2* __restrict__ stats) {
    const int wave = threadIdx.x >> 6;
    const int lane = threadIdx.x & 63;
    const int row  = blockIdx.x * 4 + wave;   // grid = B*SEQ/4 blocks of 256

    const float4* xr = (const float4*)(x + (long)row * DIM);
    float s = 0.f, ss = 0.f;
#pragma unroll
    for (int j = 0; j < 4; ++j) {
        float4 v = xr[j * 64 + lane];
        s  += v.x + v.y + v.z + v.w;
        ss += v.x * v.x + v.y * v.y + v.z * v.z + v.w * v.w;
    }
#pragma unroll
    for (int off = 32; off > 0; off >>= 1) {
        s  += __shfl_down(s, off);
        ss += __shfl_down(ss, off);
    }
    if (lane == 0) {
        float mean = s * (1.f / DIM);
        float var  = ss * (1.f / DIM) - mean * mean;
        stats[row] = make_float2(mean, rsqrtf(var + LN_EPS));
    }
}

// ---------------------------------------------------------------------------
// K2: local EMA scan within a chunk (zero initial state) + residual.
// Block = (b, chunk, 256-channel group); thread = one channel.
// ---------------------------------------------------------------------------
__global__ void local_scan_kernel(const float* __restrict__ x,
                                  const float2* __restrict__ stats,
                                  const float* __restrict__ gamma,
                                  const float* __restrict__ beta,
                                  const float* __restrict__ alphas,
                                  const float* __restrict__ paramD,
                                  float* __restrict__ out,
                                  float* __restrict__ carry) {
    const int bid   = blockIdx.x;            // [0, B*NCHUNK*4)
    const int group = bid & 3;
    const int chunk = (bid >> 2) & (NCHUNK - 1);
    const int b     = bid >> 9;

    const int c = group * 256 + threadIdx.x;
    const int h = c >> 7;                    // head = c / 128

    const float a = 1.f / (1.f + expf(-alphas[h]));
    const float r = 1.f - a;
    const float g  = gamma[c];
    const float be = beta[c];
    const float D  = paramD[c];

    const int  rowbase = b * SEQ + chunk * CLEN;
    long       idx     = (long)rowbase * DIM + c;

    float y = 0.f;
#pragma unroll 4
    for (int i = 0; i < CLEN; ++i) {
        float2 st = stats[rowbase + i];
        float xv  = x[idx];
        float u   = (xv - st.x) * st.y * g + be;
        y = r * y + a * u;
        out[idx] = y + u * D;
        idx += DIM;
    }
    carry[((long)(b * NCHUNK + chunk)) * DIM + c] = y;
}

// ---------------------------------------------------------------------------
// K3: serial scan of chunk carries per channel (tiny: 4096 threads x 128).
// excl[k] = Y_{k-1} (exclusive), Y_k = r^CLEN * Y_{k-1} + local_end_k.
// ---------------------------------------------------------------------------
__global__ void carry_scan_kernel(const float* __restrict__ alphas,
                                  const float* __restrict__ carry,
                                  float* __restrict__ excl) {
    const int tid = blockIdx.x * blockDim.x + threadIdx.x;  // [0, B*DIM)
    const int c = tid & (DIM - 1);
    const int b = tid >> 10;
    const int h = c >> 7;

    const float a  = 1.f / (1.f + expf(-alphas[h]));
    const float r  = 1.f - a;
    const float rn = powf(r, (float)CLEN);

    float Y = 0.f;
    for (int k = 0; k < NCHUNK; ++k) {
        long idx = ((long)(b * NCHUNK + k)) * DIM + c;
        float loc = carry[idx];
        excl[idx] = Y;
        Y = rn * Y + loc;
    }
}

// ---------------------------------------------------------------------------
// K4: out[b,t,c] += r^(i+1) * Y_excl[b, chunk, c], i = t % CLEN.
// One float4 per thread; each block covers exactly one (b,t) row.
// ---------------------------------------------------------------------------
__global__ void fixup_kernel(const float* __restrict__ alphas,
                             const float* __restrict__ excl,
                             float* __restrict__ out) {
    __shared__ float pw[HEADS * CLEN];
    for (int j = threadIdx.x; j < HEADS * CLEN; j += blockDim.x) {
        int hh = j / CLEN;
        int ii = j % CLEN;
        float a = 1.f / (1.f + expf(-alphas[hh]));
        pw[j] = powf(1.f - a, (float)(ii + 1));
    }
    __syncthreads();

    const long e   = ((long)blockIdx.x * blockDim.x + threadIdx.x) * 4;
    const int  c   = (int)(e & (DIM - 1));
    const long row = e >> 10;
    const int  t   = (int)(row & (SEQ - 1));
    const int  b   = (int)(row >> 13);
    const int  chunk = t / CLEN;
    const int  i     = t % CLEN;
    const int  h     = c >> 7;

    const float f = pw[h * CLEN + i];
    const float4 Y4 = *(const float4*)(excl + ((long)(b * NCHUNK + chunk)) * DIM + c);
    float4 o = *(float4*)(out + e);
    o.x += f * Y4.x;
    o.y += f * Y4.y;
    o.z += f * Y4.z;
    o.w += f * Y4.w;
    *(float4*)(out + e) = o;
}

// ---------------------------------------------------------------------------
extern "C" void kernel_launch(void* const* d_in, const int* in_sizes, int n_in,
                              void* d_out, int out_size, void* d_ws, size_t ws_size,
                              hipStream_t stream) {
    const float* x      = (const float*)d_in[0];
    const float* gamma  = (const float*)d_in[1];
    const float* beta   = (const float*)d_in[2];
    const float* alphas = (const float*)d_in[3];
    const float* paramD = (const float*)d_in[4];
    float* out = (float*)d_out;

    char* ws = (char*)d_ws;
    float2* stats = (float2*)ws;                              // 32768 * 8B = 256 KB
    float*  carry = (float*)(ws + (1 << 18));                 // 2 MB
    float*  excl  = (float*)(ws + (1 << 18) + (1 << 21));     // 2 MB

    ln_stats_kernel<<<B * SEQ / 4, 256, 0, stream>>>(x, stats);
    local_scan_kernel<<<B * NCHUNK * 4, 256, 0, stream>>>(
        x, stats, gamma, beta, alphas, paramD, out, carry);
    carry_scan_kernel<<<B * DIM / 256, 256, 0, stream>>>(alphas, carry, excl);
    fixup_kernel<<<(B * SEQ * (DIM / 4)) / 256, 256, 0, stream>>>(alphas, excl, out);
}

// Round 2
// 279.088 us; speedup vs baseline: 1.2399x; 1.2399x over previous
//
#include <hip/hip_runtime.h>
#include <math.h>

#define B 4
#define SEQ 8192
#define DIM 1024
#define HEADS 8
#define NCHUNK 128
#define CLEN (SEQ / NCHUNK)   // 64 rows per chunk
#define LN_EPS 1e-5f

// ---------------------------------------------------------------------------
// Pass 1: fused LayerNorm-stats + local EMA carry (zero initial state).
// Block = (b, chunk): 256 threads x float4 = all 1024 channels, CLEN rows.
// Per row: block-wide mean/var reduction (wave shfl + 1 barrier,
// double-buffered LDS slots), then 4 independent EMA chains per thread.
// Next row's x-load is prefetched BEFORE the barrier to hide HBM latency.
// ---------------------------------------------------------------------------
__global__ void __launch_bounds__(256) pass1_kernel(
        const float* __restrict__ x,
        const float* __restrict__ gamma,
        const float* __restrict__ beta,
        const float* __restrict__ alphas,
        float2* __restrict__ stats,
        float4* __restrict__ carry) {
    const int bid   = blockIdx.x;              // b*NCHUNK + chunk
    const int chunk = bid & (NCHUNK - 1);
    const int b     = bid >> 7;
    const int t     = threadIdx.x;
    const int c     = t * 4;
    const int h     = c >> 7;                  // 4 channels share one head
    const int wave  = t >> 6;
    const int lane  = t & 63;

    const float a = 1.f / (1.f + expf(-alphas[h]));
    const float r = 1.f - a;
    const float4 g  = *(const float4*)(gamma + c);
    const float4 be = *(const float4*)(beta + c);

    __shared__ float red[2][8];                // [row parity][4 waves x {s,ss}]

    const int rowbase = b * SEQ + chunk * CLEN;
    const float4* xp = (const float4*)x + (long)rowbase * (DIM / 4) + t;

    float4 y = make_float4(0.f, 0.f, 0.f, 0.f);
    float4 xv = xp[0];

    for (int i = 0; i < CLEN; ++i) {
        // prefetch next row before the barrier (clamped: redundant on last)
        const int ip = (i + 1 < CLEN) ? i + 1 : CLEN - 1;
        float4 xnext = xp[ip * (DIM / 4)];

        float s  = xv.x + xv.y + xv.z + xv.w;
        float ss = xv.x * xv.x + xv.y * xv.y + xv.z * xv.z + xv.w * xv.w;
#pragma unroll
        for (int off = 32; off > 0; off >>= 1) {
            s  += __shfl_down(s, off);
            ss += __shfl_down(ss, off);
        }
        const int par = i & 1;
        if (lane == 0) {
            red[par][wave]     = s;
            red[par][4 + wave] = ss;
        }
        __syncthreads();
        const float S    = red[par][0] + red[par][1] + red[par][2] + red[par][3];
        const float SS   = red[par][4] + red[par][5] + red[par][6] + red[par][7];
        const float mean = S * (1.f / DIM);
        const float var  = SS * (1.f / DIM) - mean * mean;
        const float rstd = rsqrtf(var + LN_EPS);
        if (t == 0) stats[rowbase + i] = make_float2(mean, rstd);

        float4 u;
        u.x = (xv.x - mean) * rstd * g.x + be.x;
        u.y = (xv.y - mean) * rstd * g.y + be.y;
        u.z = (xv.z - mean) * rstd * g.z + be.z;
        u.w = (xv.w - mean) * rstd * g.w + be.w;
        y.x = r * y.x + a * u.x;
        y.y = r * y.y + a * u.y;
        y.z = r * y.z + a * u.z;
        y.w = r * y.w + a * u.w;

        xv = xnext;
    }
    carry[(long)bid * (DIM / 4) + t] = y;
}

// ---------------------------------------------------------------------------
// Pass 2 (tiny): serial scan of chunk carries per channel.
// excl[k] = Y_{k-1};  Y_k = r^CLEN * Y_{k-1} + L_k.  r^64 via 6 squarings.
// ---------------------------------------------------------------------------
__global__ void carry_scan_kernel(const float* __restrict__ alphas,
                                  const float* __restrict__ carry,
                                  float* __restrict__ excl) {
    const int tid = blockIdx.x * blockDim.x + threadIdx.x;  // [0, B*DIM)
    const int c = tid & (DIM - 1);
    const int b = tid >> 10;
    const int h = c >> 7;

    const float a = 1.f / (1.f + expf(-alphas[h]));
    const float r = 1.f - a;
    float rn = r;                        // r^64 = r squared 6 times
#pragma unroll
    for (int q = 0; q < 6; ++q) rn = rn * rn;

    const float* cp = carry + (long)b * NCHUNK * DIM + c;
    float*       ep = excl  + (long)b * NCHUNK * DIM + c;

    float Y = 0.f;
#pragma unroll 8
    for (int k = 0; k < NCHUNK; ++k) {
        float loc = cp[(long)k * DIM];
        ep[(long)k * DIM] = Y;
        Y = rn * Y + loc;
    }
}

// ---------------------------------------------------------------------------
// Pass 3: final scan seeded with the true cross-chunk carry; writes out once.
// No power table, no out re-read. Same block layout as pass 1.
// ---------------------------------------------------------------------------
__global__ void __launch_bounds__(256) pass2_kernel(
        const float* __restrict__ x,
        const float2* __restrict__ stats,
        const float* __restrict__ gamma,
        const float* __restrict__ beta,
        const float* __restrict__ alphas,
        const float* __restrict__ paramD,
        const float4* __restrict__ excl,
        float4* __restrict__ out) {
    const int bid   = blockIdx.x;              // b*NCHUNK + chunk
    const int chunk = bid & (NCHUNK - 1);
    const int b     = bid >> 7;
    const int t     = threadIdx.x;
    const int c     = t * 4;
    const int h     = c >> 7;

    const float a = 1.f / (1.f + expf(-alphas[h]));
    const float r = 1.f - a;
    const float4 g  = *(const float4*)(gamma  + c);
    const float4 be = *(const float4*)(beta   + c);
    const float4 D  = *(const float4*)(paramD + c);

    const int rowbase = b * SEQ + chunk * CLEN;
    const float4* xp = (const float4*)x + (long)rowbase * (DIM / 4) + t;
    float4*       op = (float4*)out     + (long)rowbase * (DIM / 4) + t;

    float4 y = excl[(long)bid * (DIM / 4) + t];

#pragma unroll 4
    for (int i = 0; i < CLEN; ++i) {
        const float2 st = stats[rowbase + i];   // block-uniform -> scalar load
        float4 xv = xp[i * (DIM / 4)];
        float4 u, o;
        u.x = (xv.x - st.x) * st.y * g.x + be.x;
        u.y = (xv.y - st.x) * st.y * g.y + be.y;
        u.z = (xv.z - st.x) * st.y * g.z + be.z;
        u.w = (xv.w - st.x) * st.y * g.w + be.w;
        y.x = r * y.x + a * u.x;
        y.y = r * y.y + a * u.y;
        y.z = r * y.z + a * u.z;
        y.w = r * y.w + a * u.w;
        o.x = y.x + u.x * D.x;
        o.y = y.y + u.y * D.y;
        o.z = y.z + u.z * D.z;
        o.w = y.w + u.w * D.w;
        op[i * (DIM / 4)] = o;
    }
}

// ---------------------------------------------------------------------------
extern "C" void kernel_launch(void* const* d_in, const int* in_sizes, int n_in,
                              void* d_out, int out_size, void* d_ws, size_t ws_size,
                              hipStream_t stream) {
    const float* x      = (const float*)d_in[0];
    const float* gamma  = (const float*)d_in[1];
    const float* beta   = (const float*)d_in[2];
    const float* alphas = (const float*)d_in[3];
    const float* paramD = (const float*)d_in[4];
    float* out = (float*)d_out;

    char* ws = (char*)d_ws;
    float2* stats = (float2*)ws;                              // 256 KB
    float*  carry = (float*)(ws + (1 << 18));                 // 2 MB
    float*  excl  = (float*)(ws + (1 << 18) + (1 << 21));     // 2 MB

    pass1_kernel<<<B * NCHUNK, 256, 0, stream>>>(
        x, gamma, beta, alphas, stats, (float4*)carry);
    carry_scan_kernel<<<B * DIM / 256, 256, 0, stream>>>(alphas, carry, excl);
    pass2_kernel<<<B * NCHUNK, 256, 0, stream>>>(
        x, stats, gamma, beta, alphas, paramD, (const float4*)excl, (float4*)out);
}